// Round 5
// baseline (151.769 us; speedup 1.0000x reference)
//
#include <hip/hip_runtime.h>
#include <hip/hip_bf16.h>

// Problem constants
#define Bn 8
#define Tn 2048
#define En 512
#define Hn 16
#define Dn 32
#define NC 32          // scan chunks
#define CL 64          // chunk length (Tn/NC)
#define TCH 256        // tokens per bilinear block
#define INV_DECAY (1.0f/1.2f)

typedef __attribute__((ext_vector_type(8))) short  bf16x8;  // 8 bf16 (4 VGPRs)
typedef __attribute__((ext_vector_type(4))) float  f32x4;
typedef __attribute__((ext_vector_type(8))) unsigned short u16x8;

__device__ __forceinline__ unsigned short f2b(float f) {
    __hip_bfloat16 h = __float2bfloat16(f);   // RNE
    return *reinterpret_cast<unsigned short*>(&h);
}
__device__ __forceinline__ float b2f(unsigned short u) {
    union { unsigned int i; float f; } c; c.i = ((unsigned int)u) << 16; return c.f;
}

// ---------------- K0: prep — C f32->bf16 (blocks 0..255) ; W transpose->bf16 (256..511)
__global__ __launch_bounds__(256) void prep_k(const float* __restrict__ C,
                                              unsigned short* __restrict__ Cb,
                                              const float* __restrict__ W,
                                              unsigned short* __restrict__ Wt) {
    __shared__ float tile[32][33];
    if (blockIdx.x < 256) {
        int idx = blockIdx.x * 256 + threadIdx.x;   // 8 elems per thread
        const float4* p = reinterpret_cast<const float4*>(C) + (size_t)idx * 2;
        float4 a = p[0], b = p[1];
        u16x8 st;
        st[0]=f2b(a.x); st[1]=f2b(a.y); st[2]=f2b(a.z); st[3]=f2b(a.w);
        st[4]=f2b(b.x); st[5]=f2b(b.y); st[6]=f2b(b.z); st[7]=f2b(b.w);
        *reinterpret_cast<u16x8*>(Cb + (size_t)idx * 8) = st;
    } else {
        const int bid = blockIdx.x - 256;
        const int kb = (bid & 15) * 32, nb = (bid >> 4) * 32;
        const int tx = threadIdx.x & 31, ty = threadIdx.x >> 5;   // ty 0..7
        #pragma unroll
        for (int j = 0; j < 4; j++)
            tile[ty + 8 * j][tx] = W[(size_t)(kb + ty + 8 * j) * En + nb + tx];
        __syncthreads();
        #pragma unroll
        for (int j = 0; j < 4; j++)
            Wt[(size_t)(nb + ty + 8 * j) * En + kb + tx] = f2b(tile[tx][ty + 8 * j]);
    }
}

// ---------------- K1: h = x @ W + b  (bf16 MFMA GEMM, f32 accumulate) --------
__global__ __launch_bounds__(256) void gemm_mfma_k(const float* __restrict__ x,
                                                   const unsigned short* __restrict__ Wt,
                                                   const float* __restrict__ bias,
                                                   unsigned short* __restrict__ h) {
    __shared__ unsigned short As[128][40];
    __shared__ unsigned short Bs[64][40];
    const int m0 = blockIdx.x * 128, n0 = blockIdx.y * 64;
    const int tid = threadIdx.x;
    const int wid = tid >> 6, lane = tid & 63;
    const int tloc = lane & 15, kgrp = lane >> 4;
    const int wr = wid >> 1, wc = wid & 1;

    const int ar = tid >> 1, ah = (tid & 1) * 16;
    const int brr = tid >> 2, bq = (tid & 3) * 8;

    f32x4 acc[4][2] = {};

    for (int k0 = 0; k0 < En; k0 += 32) {
        const float* xp = &x[(size_t)(m0 + ar) * En + k0 + ah];
        float4 a0 = reinterpret_cast<const float4*>(xp)[0];
        float4 a1 = reinterpret_cast<const float4*>(xp)[1];
        float4 a2 = reinterpret_cast<const float4*>(xp)[2];
        float4 a3 = reinterpret_cast<const float4*>(xp)[3];
        u16x8 bv = *reinterpret_cast<const u16x8*>(&Wt[(size_t)(n0 + brr) * En + k0 + bq]);
        __syncthreads();
        u16x8 w0, w1;
        w0[0]=f2b(a0.x); w0[1]=f2b(a0.y); w0[2]=f2b(a0.z); w0[3]=f2b(a0.w);
        w0[4]=f2b(a1.x); w0[5]=f2b(a1.y); w0[6]=f2b(a1.z); w0[7]=f2b(a1.w);
        w1[0]=f2b(a2.x); w1[1]=f2b(a2.y); w1[2]=f2b(a2.z); w1[3]=f2b(a2.w);
        w1[4]=f2b(a3.x); w1[5]=f2b(a3.y); w1[6]=f2b(a3.z); w1[7]=f2b(a3.w);
        *reinterpret_cast<u16x8*>(&As[ar][ah])     = w0;
        *reinterpret_cast<u16x8*>(&As[ar][ah + 8]) = w1;
        *reinterpret_cast<u16x8*>(&Bs[brr][bq])    = bv;
        __syncthreads();

        bf16x8 afr[4], bfr[2];
        #pragma unroll
        for (int m = 0; m < 4; m++)
            afr[m] = *reinterpret_cast<const bf16x8*>(&As[wr * 64 + m * 16 + tloc][kgrp * 8]);
        #pragma unroll
        for (int n = 0; n < 2; n++)
            bfr[n] = *reinterpret_cast<const bf16x8*>(&Bs[wc * 32 + n * 16 + tloc][kgrp * 8]);
        #pragma unroll
        for (int m = 0; m < 4; m++)
            #pragma unroll
            for (int n = 0; n < 2; n++)
                acc[m][n] = __builtin_amdgcn_mfma_f32_16x16x32_bf16(afr[m], bfr[n], acc[m][n], 0, 0, 0);
    }

    #pragma unroll
    for (int n = 0; n < 2; n++) {
        const int col = n0 + wc * 32 + n * 16 + tloc;
        const float bcol = bias[col];
        #pragma unroll
        for (int m = 0; m < 4; m++)
            #pragma unroll
            for (int r = 0; r < 4; r++) {
                const int row = m0 + wr * 64 + m * 16 + kgrp * 4 + r;
                h[(size_t)row * En + col] = f2b(acc[m][n][r] + bcol);
            }
    }
}

// ---------------- K2a: per-chunk local decayed sums (bf16 h) ----------------
__global__ __launch_bounds__(512) void scan_local_k(const unsigned short* __restrict__ h,
                                                    float* __restrict__ locals) {
    const int c = blockIdx.x, b = blockIdx.y;
    const int e = threadIdx.x;
    const unsigned short* hp = h + ((size_t)(b * Tn + c * CL)) * En + e;
    float s = 0.f;
    for (int t = 0; t < CL; t++) s = (s + b2f(hp[(size_t)t * En])) * INV_DECAY;
    locals[(size_t)(b * NC + c) * En + e] = s;
}

// ---------------- K2b: serial prefix over chunks ----------------
__global__ __launch_bounds__(512) void scan_prefix_k(const float* __restrict__ locals,
                                                     float* __restrict__ Acar) {
    const int b = blockIdx.x;
    const int e = threadIdx.x;
    float invRL = 1.f;
    #pragma unroll
    for (int i = 0; i < CL; i++) invRL *= INV_DECAY;
    float A = 0.f;
    for (int c = 0; c < NC; c++) {
        Acar[(size_t)(b * NC + c) * En + e] = A;
        A = A * invRL + locals[(size_t)(b * NC + c) * En + e];
    }
}

// ---------------- K2c: emit S (bf16) for every token ------------------------
__global__ __launch_bounds__(512) void scan_emit_k(const unsigned short* __restrict__ h,
                                                   const float* __restrict__ Acar,
                                                   unsigned short* __restrict__ Sg) {
    const int c = blockIdx.x, b = blockIdx.y;
    const int e = threadIdx.x;
    float s = Acar[(size_t)(b * NC + c) * En + e];
    const size_t base = ((size_t)(b * Tn + c * CL)) * En + e;
    for (int t = 0; t < CL; t++) {
        Sg[base + (size_t)t * En] = f2b(s);
        s = (s + b2f(h[base + (size_t)t * En])) * INV_DECAY;
    }
}

// ---------------- K3: bilinear v4 — C in LDS (swizzled), h/S in regs --------
// Block: 256 thr = 4 waves x 64 tokens, 1 head. C head-slice (64KB) staged in
// LDS once, reused by all 4 waves. y = bilinear + h, in-place on h.
// Swizzle: final byte offset ^= ((k&7)<<4), applied last on BOTH sides.
__global__ __launch_bounds__(256) void bilinear4_k(unsigned short* __restrict__ hio,
                                                   const unsigned short* __restrict__ Sg,
                                                   const unsigned short* __restrict__ Cb) {
    __shared__ unsigned short Cs[32768];   // 64 KB; aliased as f32 ys[] after main loop

    const int hd = blockIdx.y;
    const int tid = threadIdx.x;
    const int wid = tid >> 6, lane = tid & 63;
    const int tloc = lane & 15, kgrp = lane >> 4;
    const int j0 = kgrp * 8;
    const int tokens0 = blockIdx.x * TCH + wid * 64;

    // ---- stage C[hd] into LDS, swizzled: 4096 chunks of 16B, 16/thread ----
    {
        const unsigned short* src = Cb + (size_t)hd * 32768;
        char* dst = reinterpret_cast<char*>(Cs);
        #pragma unroll
        for (int p = 0; p < 16; p++) {
            const int c = p * 256 + tid;                 // chunk: k=c>>7, i=(c>>2)&31, jq=c&3
            u16x8 v = *reinterpret_cast<const u16x8*>(src + c * 8);
            const int byte = (c << 4) ^ (((c >> 7) & 7) << 4);
            *reinterpret_cast<u16x8*>(dst + byte) = v;
        }
    }

    // ---- h rows + S fragments in registers (4 m-tiles x 16 tokens) ----
    u16x8 hreg[4][4];
    float sf[4][8];
    #pragma unroll
    for (int m = 0; m < 4; m++) {
        const int trow = tokens0 + m * 16 + tloc;
        const unsigned short* hrow = hio + (size_t)trow * En + hd * Dn;
        #pragma unroll
        for (int q = 0; q < 4; q++)
            hreg[m][q] = *reinterpret_cast<const u16x8*>(hrow + q * 8);
        u16x8 sv = *reinterpret_cast<const u16x8*>(Sg + (size_t)trow * En + hd * Dn + j0);
        #pragma unroll
        for (int e = 0; e < 8; e++) sf[m][e] = b2f(sv[e]);
    }
    __syncthreads();   // C staged (waits lgkmcnt), all waves may read

    // ---- main loop: B-frags from LDS, A generated in-register ----
    f32x4 acc[4][2] = {};
    const char* csb = reinterpret_cast<const char*>(Cs);
    const int bn0 = tloc * 2048 + kgrp * 16;    // unswizzled base, k=tloc
    const int swz = (tloc & 7) << 4;

    #pragma unroll 4
    for (int i = 0; i < Dn; i++) {
        const int a0 = (bn0 + i * 64) ^ swz;    // XOR applied LAST (matches write)
        bf16x8 b0 = *reinterpret_cast<const bf16x8*>(csb + a0);
        bf16x8 b1 = *reinterpret_cast<const bf16x8*>(csb + a0 + 32768);  // k=tloc+16
        #pragma unroll
        for (int m = 0; m < 4; m++) {
            const float hsc = b2f(hreg[m][i >> 3][i & 7]);
            bf16x8 a;
            #pragma unroll
            for (int e = 0; e < 8; e++) a[e] = (short)f2b(hsc * sf[m][e]);
            acc[m][0] = __builtin_amdgcn_mfma_f32_16x16x32_bf16(a, b0, acc[m][0], 0, 0, 0);
            acc[m][1] = __builtin_amdgcn_mfma_f32_16x16x32_bf16(a, b1, acc[m][1], 0, 0, 0);
        }
    }
    __syncthreads();   // all waves done READING Cs before we overwrite it

    // ---- epilogue: transpose via LDS (aliased onto Cs), +residual, store ----
    float* ys = reinterpret_cast<float*>(Cs);   // [4][64][33] f32 = 33.8KB < 64KB
    #pragma unroll
    for (int m = 0; m < 4; m++)
        #pragma unroll
        for (int nt = 0; nt < 2; nt++)
            #pragma unroll
            for (int r = 0; r < 4; r++)
                ys[(wid * 64 + m * 16 + kgrp * 4 + r) * 33 + nt * 16 + tloc] = acc[m][nt][r];
    __syncthreads();

    {
        const int row = lane;                       // 64 rows per wave
        const float* yrow = &ys[(wid * 64 + row) * 33];
        unsigned short* orow = hio + (size_t)(tokens0 + row) * En + hd * Dn;
        u16x8 hres0 = *reinterpret_cast<const u16x8*>(orow);
        u16x8 hres1 = *reinterpret_cast<const u16x8*>(orow + 8);
        u16x8 hres2 = *reinterpret_cast<const u16x8*>(orow + 16);
        u16x8 hres3 = *reinterpret_cast<const u16x8*>(orow + 24);
        u16x8 st0, st1, st2, st3;
        #pragma unroll
        for (int e = 0; e < 8; e++) {
            st0[e] = f2b(yrow[e]      + b2f(hres0[e]));
            st1[e] = f2b(yrow[8 + e]  + b2f(hres1[e]));
            st2[e] = f2b(yrow[16 + e] + b2f(hres2[e]));
            st3[e] = f2b(yrow[24 + e] + b2f(hres3[e]));
        }
        *reinterpret_cast<u16x8*>(orow)      = st0;
        *reinterpret_cast<u16x8*>(orow + 8)  = st1;
        *reinterpret_cast<u16x8*>(orow + 16) = st2;
        *reinterpret_cast<u16x8*>(orow + 24) = st3;
    }
}

// ---------------- K4: LayerNorm over E=512 (bf16 in, f32 out) ----------------
__global__ __launch_bounds__(256) void ln_k(const unsigned short* __restrict__ y,
                                            const float* __restrict__ gamma,
                                            const float* __restrict__ beta,
                                            float* __restrict__ out) {
    const int row = blockIdx.x * 4 + (threadIdx.x >> 6);
    const int lane = threadIdx.x & 63;
    const unsigned short* yp = y + (size_t)row * En;
    u16x8 v = reinterpret_cast<const u16x8*>(yp)[lane];
    float f[8];
    float s = 0.f, s2 = 0.f;
    #pragma unroll
    for (int e = 0; e < 8; e++) {
        f[e] = b2f(v[e]);
        s += f[e]; s2 += f[e] * f[e];
    }
    #pragma unroll
    for (int off = 1; off < 64; off <<= 1) {
        s  += __shfl_xor(s, off);
        s2 += __shfl_xor(s2, off);
    }
    const float mu = s * (1.f / En);
    const float var = s2 * (1.f / En) - mu * mu;
    const float rs = rsqrtf(var + 1e-3f);
    const int cbase = lane * 8;
    float4 g0 = reinterpret_cast<const float4*>(&gamma[cbase])[0];
    float4 g1 = reinterpret_cast<const float4*>(&gamma[cbase])[1];
    float4 b0 = reinterpret_cast<const float4*>(&beta[cbase])[0];
    float4 b1 = reinterpret_cast<const float4*>(&beta[cbase])[1];
    float4 o0, o1;
    o0.x = (f[0] - mu) * rs * g0.x + b0.x; o0.y = (f[1] - mu) * rs * g0.y + b0.y;
    o0.z = (f[2] - mu) * rs * g0.z + b0.z; o0.w = (f[3] - mu) * rs * g0.w + b0.w;
    o1.x = (f[4] - mu) * rs * g1.x + b1.x; o1.y = (f[5] - mu) * rs * g1.y + b1.y;
    o1.z = (f[6] - mu) * rs * g1.z + b1.z; o1.w = (f[7] - mu) * rs * g1.w + b1.w;
    float* op = out + (size_t)row * En;
    reinterpret_cast<float4*>(op)[lane * 2]     = o0;
    reinterpret_cast<float4*>(op)[lane * 2 + 1] = o1;
}

extern "C" void kernel_launch(void* const* d_in, const int* in_sizes, int n_in,
                              void* d_out, int out_size, void* d_ws, size_t ws_size,
                              hipStream_t stream) {
    const float* x     = (const float*)d_in[0];
    const float* W     = (const float*)d_in[1];
    const float* bias  = (const float*)d_in[2];
    const float* C     = (const float*)d_in[3];
    const float* gamma = (const float*)d_in[4];
    const float* beta  = (const float*)d_in[5];
    float* out = (float*)d_out;

    unsigned short* hb  = (unsigned short*)d_ws;
    unsigned short* Sg  = hb + (size_t)Bn * Tn * En;
    unsigned short* Cbf = Sg + (size_t)Bn * Tn * En;
    unsigned short* Wt  = Cbf + (size_t)Hn * Dn * Dn * Dn;
    float* locals = (float*)(Wt + (size_t)En * En);
    float* Acar   = locals + (size_t)Bn * NC * En;

    prep_k<<<512, 256, 0, stream>>>(C, Cbf, W, Wt);
    gemm_mfma_k<<<dim3((Bn * Tn) / 128, En / 64), 256, 0, stream>>>(x, Wt, bias, hb);
    scan_local_k<<<dim3(NC, Bn), 512, 0, stream>>>(hb, locals);
    scan_prefix_k<<<Bn, 512, 0, stream>>>(locals, Acar);
    scan_emit_k<<<dim3(NC, Bn), 512, 0, stream>>>(hb, Acar, Sg);
    bilinear4_k<<<dim3((Bn * Tn) / TCH, Hn), 256, 0, stream>>>(hb, Sg, Cbf);
    ln_k<<<(Bn * Tn) / 4, 256, 0, stream>>>(hb, gamma, beta, out);
}

// Round 6
// 100.802 us; speedup vs baseline: 1.5056x; 1.5056x over previous
//
#include <hip/hip_runtime.h>
#include <hip/hip_bf16.h>

// Problem constants
#define Bn 8
#define Tn 2048
#define En 512
#define Hn 16
#define Dn 32
#define NC 32          // scan chunks
#define CL 64          // chunk length (Tn/NC)
#define TCH 512        // tokens per bilinear block (8 waves x 64)
#define INV_DECAY (1.0f/1.2f)

typedef __attribute__((ext_vector_type(8))) short  bf16x8;  // 8 bf16 (4 VGPRs)
typedef __attribute__((ext_vector_type(4))) float  f32x4;
typedef __attribute__((ext_vector_type(8))) unsigned short u16x8;

__device__ __forceinline__ unsigned short f2b(float f) {
    __hip_bfloat16 h = __float2bfloat16(f);   // RNE
    return *reinterpret_cast<unsigned short*>(&h);
}
__device__ __forceinline__ float b2f(unsigned short u) {
    union { unsigned int i; float f; } c; c.i = ((unsigned int)u) << 16; return c.f;
}

// ---------------- K0: prep --------------------------------------------------
// blocks 0..255: relayout C f32 -> bf16 per-lane-contiguous LDS image:
//   16B chunk g = ((hd*32 + i)*2 + half)*64 + lane,  lane=(kgrp<<4)|tloc
//   content    = C[hd][k=half*16+tloc][i][kgrp*8 .. +7]
// blocks 256..511: W[k][n] f32 -> Wt[n][k] bf16 (transpose).
__global__ __launch_bounds__(256) void prep_k(const float* __restrict__ C,
                                              unsigned short* __restrict__ Cl,
                                              const float* __restrict__ W,
                                              unsigned short* __restrict__ Wt) {
    __shared__ float tile[32][33];
    if (blockIdx.x < 256) {
        const int g = blockIdx.x * 256 + threadIdx.x;   // 65536 chunks
        const int hd = g >> 12, rem = g & 4095;
        const int i = rem >> 7, half = (rem >> 6) & 1, lane = rem & 63;
        const int tloc = lane & 15, kgrp = lane >> 4;
        const int k = half * 16 + tloc;
        const float* src = C + (size_t)hd * 32768 + (size_t)k * 1024 + i * 32 + kgrp * 8;
        float4 a = reinterpret_cast<const float4*>(src)[0];
        float4 b = reinterpret_cast<const float4*>(src)[1];
        u16x8 st;
        st[0]=f2b(a.x); st[1]=f2b(a.y); st[2]=f2b(a.z); st[3]=f2b(a.w);
        st[4]=f2b(b.x); st[5]=f2b(b.y); st[6]=f2b(b.z); st[7]=f2b(b.w);
        *reinterpret_cast<u16x8*>(Cl + (size_t)g * 8) = st;
    } else {
        const int bid = blockIdx.x - 256;
        const int kb = (bid & 15) * 32, nb = (bid >> 4) * 32;
        const int tx = threadIdx.x & 31, ty = threadIdx.x >> 5;   // ty 0..7
        #pragma unroll
        for (int j = 0; j < 4; j++)
            tile[ty + 8 * j][tx] = W[(size_t)(kb + ty + 8 * j) * En + nb + tx];
        __syncthreads();
        #pragma unroll
        for (int j = 0; j < 4; j++)
            Wt[(size_t)(nb + ty + 8 * j) * En + kb + tx] = f2b(tile[tx][ty + 8 * j]);
    }
}

// ---------------- K1: h = x @ W + b  (bf16 MFMA GEMM, f32 accumulate) --------
__global__ __launch_bounds__(256) void gemm_mfma_k(const float* __restrict__ x,
                                                   const unsigned short* __restrict__ Wt,
                                                   const float* __restrict__ bias,
                                                   unsigned short* __restrict__ h) {
    __shared__ unsigned short As[128][40];
    __shared__ unsigned short Bs[64][40];
    const int m0 = blockIdx.x * 128, n0 = blockIdx.y * 64;
    const int tid = threadIdx.x;
    const int wid = tid >> 6, lane = tid & 63;
    const int tloc = lane & 15, kgrp = lane >> 4;
    const int wr = wid >> 1, wc = wid & 1;

    const int ar = tid >> 1, ah = (tid & 1) * 16;
    const int brr = tid >> 2, bq = (tid & 3) * 8;

    f32x4 acc[4][2] = {};

    for (int k0 = 0; k0 < En; k0 += 32) {
        const float* xp = &x[(size_t)(m0 + ar) * En + k0 + ah];
        float4 a0 = reinterpret_cast<const float4*>(xp)[0];
        float4 a1 = reinterpret_cast<const float4*>(xp)[1];
        float4 a2 = reinterpret_cast<const float4*>(xp)[2];
        float4 a3 = reinterpret_cast<const float4*>(xp)[3];
        u16x8 bv = *reinterpret_cast<const u16x8*>(&Wt[(size_t)(n0 + brr) * En + k0 + bq]);
        __syncthreads();
        u16x8 w0, w1;
        w0[0]=f2b(a0.x); w0[1]=f2b(a0.y); w0[2]=f2b(a0.z); w0[3]=f2b(a0.w);
        w0[4]=f2b(a1.x); w0[5]=f2b(a1.y); w0[6]=f2b(a1.z); w0[7]=f2b(a1.w);
        w1[0]=f2b(a2.x); w1[1]=f2b(a2.y); w1[2]=f2b(a2.z); w1[3]=f2b(a2.w);
        w1[4]=f2b(a3.x); w1[5]=f2b(a3.y); w1[6]=f2b(a3.z); w1[7]=f2b(a3.w);
        *reinterpret_cast<u16x8*>(&As[ar][ah])     = w0;
        *reinterpret_cast<u16x8*>(&As[ar][ah + 8]) = w1;
        *reinterpret_cast<u16x8*>(&Bs[brr][bq])    = bv;
        __syncthreads();

        bf16x8 afr[4], bfr[2];
        #pragma unroll
        for (int m = 0; m < 4; m++)
            afr[m] = *reinterpret_cast<const bf16x8*>(&As[wr * 64 + m * 16 + tloc][kgrp * 8]);
        #pragma unroll
        for (int n = 0; n < 2; n++)
            bfr[n] = *reinterpret_cast<const bf16x8*>(&Bs[wc * 32 + n * 16 + tloc][kgrp * 8]);
        #pragma unroll
        for (int m = 0; m < 4; m++)
            #pragma unroll
            for (int n = 0; n < 2; n++)
                acc[m][n] = __builtin_amdgcn_mfma_f32_16x16x32_bf16(afr[m], bfr[n], acc[m][n], 0, 0, 0);
    }

    #pragma unroll
    for (int n = 0; n < 2; n++) {
        const int col = n0 + wc * 32 + n * 16 + tloc;
        const float bcol = bias[col];
        #pragma unroll
        for (int m = 0; m < 4; m++)
            #pragma unroll
            for (int r = 0; r < 4; r++) {
                const int row = m0 + wr * 64 + m * 16 + kgrp * 4 + r;
                h[(size_t)row * En + col] = f2b(acc[m][n][r] + bcol);
            }
    }
}

// ---------------- K2a: per-chunk local decayed sums (bf16 h) ----------------
__global__ __launch_bounds__(512) void scan_local_k(const unsigned short* __restrict__ h,
                                                    float* __restrict__ locals) {
    const int c = blockIdx.x, b = blockIdx.y;
    const int e = threadIdx.x;
    const unsigned short* hp = h + ((size_t)(b * Tn + c * CL)) * En + e;
    float s = 0.f;
    for (int t = 0; t < CL; t++) s = (s + b2f(hp[(size_t)t * En])) * INV_DECAY;
    locals[(size_t)(b * NC + c) * En + e] = s;
}

// ---------------- K2b: serial prefix over chunks ----------------
__global__ __launch_bounds__(512) void scan_prefix_k(const float* __restrict__ locals,
                                                     float* __restrict__ Acar) {
    const int b = blockIdx.x;
    const int e = threadIdx.x;
    float invRL = 1.f;
    #pragma unroll
    for (int i = 0; i < CL; i++) invRL *= INV_DECAY;
    float A = 0.f;
    for (int c = 0; c < NC; c++) {
        Acar[(size_t)(b * NC + c) * En + e] = A;
        A = A * invRL + locals[(size_t)(b * NC + c) * En + e];
    }
}

// ---------------- K2c: emit S (bf16) for every token ------------------------
__global__ __launch_bounds__(512) void scan_emit_k(const unsigned short* __restrict__ h,
                                                   const float* __restrict__ Acar,
                                                   unsigned short* __restrict__ Sg) {
    const int c = blockIdx.x, b = blockIdx.y;
    const int e = threadIdx.x;
    float s = Acar[(size_t)(b * NC + c) * En + e];
    const size_t base = ((size_t)(b * Tn + c * CL)) * En + e;
    for (int t = 0; t < CL; t++) {
        Sg[base + (size_t)t * En] = f2b(s);
        s = (s + b2f(h[base + (size_t)t * En])) * INV_DECAY;
    }
}

// ---------------- K3: bilinear v5 — pre-permuted C in LDS, conflict-free ----
// Block: 512 thr = 8 waves x 64 tokens, 1 head. C image (64KB) staged linearly
// into LDS; lane's B-frag at (i*128 + half*64 + lane)*16B — sequential, no
// conflicts. h/S in registers. y = bilinear + h, in-place on h.
__global__ __launch_bounds__(512, 4) void bilinear5_k(unsigned short* __restrict__ hio,
                                                      const unsigned short* __restrict__ Sg,
                                                      const unsigned short* __restrict__ Cl) {
    __shared__ unsigned short Cs[32768];   // 64 KB; aliased as f32 ys[] in epilogue

    const int hd = blockIdx.y;
    const int tid = threadIdx.x;
    const int wid = tid >> 6, lane = tid & 63;
    const int tloc = lane & 15, kgrp = lane >> 4;
    const int j0 = kgrp * 8;
    const int tokens0 = blockIdx.x * TCH + wid * 64;

    // ---- stage C image: straight linear copy, 8 x 16B per thread ----
    {
        const unsigned short* src = Cl + (size_t)hd * 32768;
        #pragma unroll
        for (int p = 0; p < 8; p++) {
            const int c = p * 512 + tid;
            *reinterpret_cast<u16x8*>(&Cs[c * 8]) =
                *reinterpret_cast<const u16x8*>(src + (size_t)c * 8);
        }
    }

    // ---- h rows + S fragments in registers (4 m-tiles x 16 tokens) ----
    u16x8 hreg[4][4];
    float sf[4][8];
    #pragma unroll
    for (int m = 0; m < 4; m++) {
        const int trow = tokens0 + m * 16 + tloc;
        const unsigned short* hrow = hio + (size_t)trow * En + hd * Dn;
        #pragma unroll
        for (int q = 0; q < 4; q++)
            hreg[m][q] = *reinterpret_cast<const u16x8*>(hrow + q * 8);
        u16x8 sv = *reinterpret_cast<const u16x8*>(Sg + (size_t)trow * En + hd * Dn + j0);
        #pragma unroll
        for (int e = 0; e < 8; e++) sf[m][e] = b2f(sv[e]);
    }
    __syncthreads();   // C staged

    // ---- main loop: conflict-free LDS B-frags, in-register A-gen ----
    f32x4 acc[4][2] = {};
    #pragma unroll
    for (int i = 0; i < Dn; i++) {
        bf16x8 b0 = *reinterpret_cast<const bf16x8*>(&Cs[(i * 128 + lane) * 8]);
        bf16x8 b1 = *reinterpret_cast<const bf16x8*>(&Cs[(i * 128 + 64 + lane) * 8]);
        #pragma unroll
        for (int m = 0; m < 4; m++) {
            const float hsc = b2f(hreg[m][i >> 3][i & 7]);
            bf16x8 a;
            #pragma unroll
            for (int e = 0; e < 8; e++) a[e] = (short)f2b(hsc * sf[m][e]);
            acc[m][0] = __builtin_amdgcn_mfma_f32_16x16x32_bf16(a, b0, acc[m][0], 0, 0, 0);
            acc[m][1] = __builtin_amdgcn_mfma_f32_16x16x32_bf16(a, b1, acc[m][1], 0, 0, 0);
        }
    }
    __syncthreads();   // all waves done reading Cs

    // ---- epilogue: two-phase transpose via LDS alias, +residual, store ----
    float* ys = reinterpret_cast<float*>(Cs);   // [256][34] f32 = 34.8 KB
    const int wl = wid & 3;
    #pragma unroll
    for (int ph = 0; ph < 2; ph++) {
        if ((wid >> 2) == ph) {
            #pragma unroll
            for (int m = 0; m < 4; m++)
                #pragma unroll
                for (int nt = 0; nt < 2; nt++)
                    #pragma unroll
                    for (int r = 0; r < 4; r++)
                        ys[(wl * 64 + m * 16 + kgrp * 4 + r) * 34 + nt * 16 + tloc] = acc[m][nt][r];
        }
        __syncthreads();
        if ((wid >> 2) == ph) {
            const float* yrow = &ys[(wl * 64 + lane) * 34];
            unsigned short* orow = hio + (size_t)(tokens0 + lane) * En + hd * Dn;
            #pragma unroll
            for (int q = 0; q < 4; q++) {
                u16x8 hres = *reinterpret_cast<const u16x8*>(orow + q * 8);
                u16x8 s;
                #pragma unroll
                for (int e2 = 0; e2 < 4; e2++) {
                    float2 v = *reinterpret_cast<const float2*>(yrow + q * 8 + e2 * 2);
                    s[e2 * 2]     = f2b(v.x + b2f(hres[e2 * 2]));
                    s[e2 * 2 + 1] = f2b(v.y + b2f(hres[e2 * 2 + 1]));
                }
                *reinterpret_cast<u16x8*>(orow + q * 8) = s;
            }
        }
        __syncthreads();
    }
}

// ---------------- K4: LayerNorm over E=512 (bf16 in, f32 out) ----------------
__global__ __launch_bounds__(256) void ln_k(const unsigned short* __restrict__ y,
                                            const float* __restrict__ gamma,
                                            const float* __restrict__ beta,
                                            float* __restrict__ out) {
    const int row = blockIdx.x * 4 + (threadIdx.x >> 6);
    const int lane = threadIdx.x & 63;
    const unsigned short* yp = y + (size_t)row * En;
    u16x8 v = reinterpret_cast<const u16x8*>(yp)[lane];
    float f[8];
    float s = 0.f, s2 = 0.f;
    #pragma unroll
    for (int e = 0; e < 8; e++) {
        f[e] = b2f(v[e]);
        s += f[e]; s2 += f[e] * f[e];
    }
    #pragma unroll
    for (int off = 1; off < 64; off <<= 1) {
        s  += __shfl_xor(s, off);
        s2 += __shfl_xor(s2, off);
    }
    const float mu = s * (1.f / En);
    const float var = s2 * (1.f / En) - mu * mu;
    const float rs = rsqrtf(var + 1e-3f);
    const int cbase = lane * 8;
    float4 g0 = reinterpret_cast<const float4*>(&gamma[cbase])[0];
    float4 g1 = reinterpret_cast<const float4*>(&gamma[cbase])[1];
    float4 b0 = reinterpret_cast<const float4*>(&beta[cbase])[0];
    float4 b1 = reinterpret_cast<const float4*>(&beta[cbase])[1];
    float4 o0, o1;
    o0.x = (f[0] - mu) * rs * g0.x + b0.x; o0.y = (f[1] - mu) * rs * g0.y + b0.y;
    o0.z = (f[2] - mu) * rs * g0.z + b0.z; o0.w = (f[3] - mu) * rs * g0.w + b0.w;
    o1.x = (f[4] - mu) * rs * g1.x + b1.x; o1.y = (f[5] - mu) * rs * g1.y + b1.y;
    o1.z = (f[6] - mu) * rs * g1.z + b1.z; o1.w = (f[7] - mu) * rs * g1.w + b1.w;
    float* op = out + (size_t)row * En;
    reinterpret_cast<float4*>(op)[lane * 2]     = o0;
    reinterpret_cast<float4*>(op)[lane * 2 + 1] = o1;
}

extern "C" void kernel_launch(void* const* d_in, const int* in_sizes, int n_in,
                              void* d_out, int out_size, void* d_ws, size_t ws_size,
                              hipStream_t stream) {
    const float* x     = (const float*)d_in[0];
    const float* W     = (const float*)d_in[1];
    const float* bias  = (const float*)d_in[2];
    const float* C     = (const float*)d_in[3];
    const float* gamma = (const float*)d_in[4];
    const float* beta  = (const float*)d_in[5];
    float* out = (float*)d_out;

    unsigned short* hb  = (unsigned short*)d_ws;
    unsigned short* Sg  = hb + (size_t)Bn * Tn * En;
    unsigned short* Cl  = Sg + (size_t)Bn * Tn * En;
    unsigned short* Wt  = Cl + (size_t)Hn * Dn * Dn * Dn;
    float* locals = (float*)(Wt + (size_t)En * En);
    float* Acar   = locals + (size_t)Bn * NC * En;

    prep_k<<<512, 256, 0, stream>>>(C, Cl, W, Wt);
    gemm_mfma_k<<<dim3((Bn * Tn) / 128, En / 64), 256, 0, stream>>>(x, Wt, bias, hb);
    scan_local_k<<<dim3(NC, Bn), 512, 0, stream>>>(hb, locals);
    scan_prefix_k<<<Bn, 512, 0, stream>>>(locals, Acar);
    scan_emit_k<<<dim3(NC, Bn), 512, 0, stream>>>(hb, Acar, Sg);
    bilinear5_k<<<dim3((Bn * Tn) / TCH, Hn), 512, 0, stream>>>(hb, Sg, Cl);
    ln_k<<<(Bn * Tn) / 4, 256, 0, stream>>>(hb, gamma, beta, out);
}